// Round 2
// baseline (180.840 us; speedup 1.0000x reference)
//
#include <hip/hip_runtime.h>
#include <stdint.h>
#include <math.h>

// Kuramoto dynamics, B=65536 x N=60, 10 steps.
// R5: latency-stall fixes on top of R4's transpose-free MFMA structure.
//   R4 post-mortem: LDS/bank-conflicts -> 0 but wall flat at ~57us.
//   Occupancy 18% (=1.44 waves/SIMD) with ~50k cyc residency per wave vs
//   ~13k cyc of issue work => waves stall ~75% on in-register deps.
// Fixes:
//   (a) 256-thread blocks (4 independent waves/WG): if residency was capped
//       per-WG (~6 WGs/CU observed), this 4x's resident waves -> 4/SIMD.
//   (b) product-major S/C-interleaved MFMA order: same-acc reuse distance
//       3 -> 8 instructions, covering MFMA latency with independent issue.
//       Per-acc product ORDER unchanged (H.BH, L.BH, H.BL) -> bitwise-same.
// Numerics preserved verbatim from R3/R4:
//   - 3-pass split MFMA: AH.BH + AL.BH + AH.BL
//   - update: 4 separately-rounded f32 ops (#pragma clang fp contract(off))
//   - wrap: branch-free, boundary-exact (|x| >= f32(pi) predicate)
//   - HW __sincosf only on paths attenuated by eff_dt*scale ~1e-3

#define B_TOTAL 65536
#define NOSC 60
#define STEPS 10

using short4v = __attribute__((ext_vector_type(4))) short;
using floatx4 = __attribute__((ext_vector_type(4))) float;

#if __has_builtin(__builtin_amdgcn_perm)
__device__ __forceinline__ unsigned int perm_b32(unsigned int s0, unsigned int s1, unsigned int sel) {
    return __builtin_amdgcn_perm(s0, s1, sel);
}
#else
__device__ __forceinline__ unsigned int perm_b32(unsigned int s0, unsigned int s1, unsigned int sel) {
    unsigned long long pool = ((unsigned long long)s0 << 32) | s1;
    unsigned int r = 0;
#pragma unroll
    for (int b = 0; b < 4; ++b) {
        unsigned int s = (sel >> (8 * b)) & 0xff;
        r |= ((unsigned int)((pool >> (8 * s)) & 0xff)) << (8 * b);
    }
    return r;
}
#endif

__device__ __forceinline__ unsigned int fbits(float x)        { return __builtin_bit_cast(unsigned int, x); }
__device__ __forceinline__ float        bitsf(unsigned int u) { return __builtin_bit_cast(float, u); }

// 16x16x16 bf16 MFMA (K=16). Guarded: builtin if present, else inline asm
// (v_mfma_f32_16x16x16_bf16 exists on gfx950 per ISA ref §10).
#if __has_builtin(__builtin_amdgcn_mfma_f32_16x16x16bf16_1k)
__device__ __forceinline__ floatx4 mfma16(short4v a, short4v b, floatx4 c) {
    return __builtin_amdgcn_mfma_f32_16x16x16bf16_1k(a, b, c, 0, 0, 0);
}
#else
__device__ __forceinline__ floatx4 mfma16(short4v a, short4v b, floatx4 c) {
    asm("v_mfma_f32_16x16x16_bf16 %0, %1, %2, %0" : "+v"(c) : "v"(a), "v"(b));
    return c;
}
#endif

// pack bf16-hi(a) into low half, bf16-hi(b) into high half of one b32
__device__ __forceinline__ unsigned int pack_hi_pair(float a, float b) {
    return perm_b32(fbits(b), fbits(a), 0x07060302u);
}

__global__ __launch_bounds__(256, 4)
void kuramoto_kernel(const float* __restrict__ theta_in,
                     const float* __restrict__ Kmat,
                     const float* __restrict__ omega,
                     const float* __restrict__ p_kglobal,
                     const float* __restrict__ p_cmod,
                     const float* __restrict__ p_gate,
                     const float* __restrict__ p_slow,
                     const float* __restrict__ p_dsneg,
                     const float* __restrict__ p_relax,
                     float* __restrict__ theta_out,
                     float* __restrict__ coh_out)
{
    const int lane = threadIdx.x & 63;
    const int wid  = threadIdx.x >> 6;   // wave within block: 4 independent waves
    const int lidx = lane & 15;          // batch within tile
    const int quad = lane >> 4;          // 0..3

    const float kglobal = p_kglobal[0];
    const float cmod    = p_cmod[0];
    const float gate    = p_gate[0];
    const float slow    = p_slow[0];
    const float dsneg   = p_dsneg[0];
    const float relax   = p_relax[0];

    float eff_dt, scale;
    {
#pragma clang fp contract(off)
        const float a     = slow * relax;
        const float b     = 1.0f + a;
        const float crit  = 1.0f / b;
        eff_dt            = 0.1f * crit;
        const float boost = 1.0f + gate * dsneg;
        scale             = (kglobal * boost) / 60.0f;
    }

    const int batch0 = (blockIdx.x * 4 + wid) * 16;
    const int brow   = (batch0 + lidx) * NOSC;

    // ---- A operand (loop-invariant): Ke = K*cmod in MFMA-A layout, hi/lo split.
    // A[m=i][k=j]: lane holds row i = nt*16 + lidx, k = kt*16 + quad*4 + j.
    short4v AH[4][4], AL[4][4];
#pragma unroll
    for (int nt = 0; nt < 4; ++nt) {
        const int i = nt * 16 + lidx;
        const bool okn = (i < NOSC);          // zero A rows >= 60 -> acc rows 60..63 = 0
#pragma unroll
        for (int kt = 0; kt < 4; ++kt) {
            const int k0 = kt * 16 + quad * 4;
            float kv[4];
            if (okn && (k0 + 3) < NOSC) {
                const float4 a = *(const float4*)(Kmat + i * NOSC + k0);
                kv[0] = a.x; kv[1] = a.y; kv[2] = a.z; kv[3] = a.w;
            } else {
#pragma unroll
                for (int j = 0; j < 4; ++j)
                    kv[j] = (okn && (k0 + j) < NOSC) ? Kmat[i * NOSC + k0 + j] : 0.0f;
            }
            short4v h, l;
#pragma unroll
            for (int j = 0; j < 4; ++j) {
                const float v = kv[j] * cmod;
                const unsigned int hb = fbits(v) & 0xffff0000u;
                const float rlo = v - bitsf(hb);
                h[j] = (short)(hb >> 16);
                l[j] = (short)(fbits(rlo) >> 16);
            }
            AH[nt][kt] = h;
            AL[nt][kt] = l;
        }
    }

    // ---- state in C/D layout of the transposed GEMM:
    // element (osc o = nt*16 + quad*4 + r, batch = batch0 + lidx)
    float th[4][4], sn[4][4], cn[4][4], omg[4][4];
#pragma unroll
    for (int nt = 0; nt < 4; ++nt) {
        const int o0 = nt * 16 + quad * 4;    // o0 in {0,4,..,56} or 60 (pad)
        if (o0 + 3 < NOSC) {
            const float4 tv = *(const float4*)(theta_in + brow + o0);
            const float4 ov = *(const float4*)(omega + o0);
            th[nt][0] = tv.x; th[nt][1] = tv.y; th[nt][2] = tv.z; th[nt][3] = tv.w;
            omg[nt][0] = ov.x; omg[nt][1] = ov.y; omg[nt][2] = ov.z; omg[nt][3] = ov.w;
        } else {
#pragma unroll
            for (int r = 0; r < 4; ++r) { th[nt][r] = 0.0f; omg[nt][r] = 0.0f; }
        }
#pragma unroll
        for (int r = 0; r < 4; ++r)
            __sincosf(th[nt][r], &sn[nt][r], &cn[nt][r]);
    }

    // wrap constants (boundary-exact, see R3 notes)
    const float PI_F = 3.14159274101257324f;
    const float C_HI = 6.28318548202514648f;    // f32(2pi)
    const float C_LO = -1.7484556e-7f;          // 2pi - C_HI (f64-accurate)

    for (int t = 0; t < STEPS; ++t) {
        floatx4 accS[4], accC[4];
#pragma unroll
        for (int nt = 0; nt < 4; ++nt) { accS[nt] = (floatx4)0.0f; accC[nt] = (floatx4)0.0f; }

#pragma unroll
        for (int kt = 0; kt < 4; ++kt) {
            // B operand for k-tile kt: B[k = kt*16 + quad*4 + j][n = lidx]
            // == this thread's own state at (nt==kt, r==j). Zero data movement.
            union PU { unsigned int u[2]; short4v v; };
            PU bsh, bsl, bch, bcl;
            float slo[4], clo[4];
#pragma unroll
            for (int r = 0; r < 4; ++r) {
                const unsigned int us = fbits(sn[kt][r]);
                slo[r] = sn[kt][r] - bitsf(us & 0xffff0000u);
                const unsigned int uc = fbits(cn[kt][r]);
                clo[r] = cn[kt][r] - bitsf(uc & 0xffff0000u);
            }
            bsh.u[0] = pack_hi_pair(sn[kt][0], sn[kt][1]);
            bsh.u[1] = pack_hi_pair(sn[kt][2], sn[kt][3]);
            bsl.u[0] = pack_hi_pair(slo[0], slo[1]);
            bsl.u[1] = pack_hi_pair(slo[2], slo[3]);
            bch.u[0] = pack_hi_pair(cn[kt][0], cn[kt][1]);
            bch.u[1] = pack_hi_pair(cn[kt][2], cn[kt][3]);
            bcl.u[0] = pack_hi_pair(clo[0], clo[1]);
            bcl.u[1] = pack_hi_pair(clo[2], clo[3]);

            // product-major, S/C interleaved: same-acc reuse distance = 8 MFMAs.
            // Per-acc product order unchanged vs R4 (H.BH, L.BH, H.BL).
#pragma unroll
            for (int nt = 0; nt < 4; ++nt) accS[nt] = mfma16(AH[nt][kt], bsh.v, accS[nt]);
#pragma unroll
            for (int nt = 0; nt < 4; ++nt) accC[nt] = mfma16(AH[nt][kt], bch.v, accC[nt]);
#pragma unroll
            for (int nt = 0; nt < 4; ++nt) accS[nt] = mfma16(AL[nt][kt], bsh.v, accS[nt]);
#pragma unroll
            for (int nt = 0; nt < 4; ++nt) accC[nt] = mfma16(AL[nt][kt], bch.v, accC[nt]);
#pragma unroll
            for (int nt = 0; nt < 4; ++nt) accS[nt] = mfma16(AH[nt][kt], bsl.v, accS[nt]);
#pragma unroll
            for (int nt = 0; nt < 4; ++nt) accC[nt] = mfma16(AH[nt][kt], bcl.v, accC[nt]);
        }

        // ---- update: ref-exact association + boundary-exact wrap
#pragma unroll
        for (int nt = 0; nt < 4; ++nt) {
#pragma unroll
            for (int r = 0; r < 4; ++r) {
                const float S = accS[nt][r];
                const float C = accC[nt][r];
                const float coup = cn[nt][r] * S - sn[nt][r] * C;  // approx path: fma ok
                float nth;
                {
#pragma clang fp contract(off)
                    const float t1 = scale * coup;       // np: scale*coupling_sum
                    const float t2 = omg[nt][r] + t1;    // np: omega + ...
                    const float t3 = eff_dt * t2;        // np: eff_dt * (...)
                    nth = th[nt][r] + t3;                // np: th + ...
                }
                float n = 0.0f;
                n = (nth >=  PI_F) ?  1.0f : n;
                n = (nth <= -PI_F) ? -1.0f : n;
                float y = fmaf(n, -C_HI, nth);
                y = fmaf(n, -C_LO, y);
                th[nt][r] = y;
                __sincosf(y, &sn[nt][r], &cn[nt][r]);
            }
        }
    }

    // ---- epilogue: store wrapped theta (float4 per nt, pad tile skipped)
#pragma unroll
    for (int nt = 0; nt < 4; ++nt) {
        const int o0 = nt * 16 + quad * 4;
        if (o0 + 3 < NOSC) {
            float4 tv;
            tv.x = th[nt][0]; tv.y = th[nt][1]; tv.z = th[nt][2]; tv.w = th[nt][3];
            *(float4*)(theta_out + brow + o0) = tv;
        }
    }

    // ---- coherence: batch = lidx; thread holds 16 of its 60 osc, other 48
    // live in the 3 sibling quads -> 2 shfl_xor hops (16, 32) reduce.
    float pc = 0.0f, ps = 0.0f;
#pragma unroll
    for (int nt = 0; nt < 4; ++nt) {
        if (nt * 16 + quad * 4 < NOSC) {   // skip pad osc 60..63 (cos(0)=1!)
#pragma unroll
            for (int r = 0; r < 4; ++r) { pc += cn[nt][r]; ps += sn[nt][r]; }
        }
    }
    pc += __shfl_xor(pc, 16);
    ps += __shfl_xor(ps, 16);
    pc += __shfl_xor(pc, 32);
    ps += __shfl_xor(ps, 32);
    if (quad == 0) {
        const float cm = pc / 60.0f;
        const float sm = ps / 60.0f;
        coh_out[batch0 + lidx] = sqrtf(cm * cm + sm * sm);
    }
}

extern "C" void kernel_launch(void* const* d_in, const int* in_sizes, int n_in,
                              void* d_out, int out_size, void* d_ws, size_t ws_size,
                              hipStream_t stream) {
    const float* theta = (const float*)d_in[0];
    const float* Kmat  = (const float*)d_in[1];
    const float* omg   = (const float*)d_in[2];
    const float* kg    = (const float*)d_in[3];
    const float* cmod  = (const float*)d_in[4];
    const float* gate  = (const float*)d_in[5];
    const float* slow  = (const float*)d_in[6];
    const float* dsn   = (const float*)d_in[7];
    const float* relax = (const float*)d_in[8];
    float* out = (float*)d_out;

    kuramoto_kernel<<<dim3(B_TOTAL / 64), dim3(256), 0, stream>>>(
        theta, Kmat, omg, kg, cmod, gate, slow, dsn, relax,
        out, out + (size_t)B_TOTAL * NOSC);
}

// Round 3
// 127.966 us; speedup vs baseline: 1.4132x; 1.4132x over previous
//
#include <hip/hip_runtime.h>
#include <stdint.h>
#include <math.h>

// Kuramoto dynamics, B=65536 x N=60, 10 steps.
// R6: R5's 256-thread blocks WITHOUT the register cap.
//   R5 post-mortem: __launch_bounds__(256,4) forced VGPR 100->64 -> scratch
//   spills (FETCH 7.8MB->267MB, WRITE 15.6->97MB) -> scratch-BW-bound, 2x slower.
//   The occupancy mechanism itself worked (18%->39% even while spilling).
//   Fix: __launch_bounds__(256) only. Natural ~100 VGPR live set lands in the
//   <=128 allocation bin -> 4 waves/SIMD, 1024 blocks = 4 blocks/CU, no spills.
// Carried from R4/R5:
//   - transposed-GEMM MFMA structure (C^T layout == B-input layout, no LDS)
//   - product-major S/C-interleaved MFMA order (same-acc reuse distance 8)
// Numerics preserved verbatim from R3:
//   - 3-pass split MFMA: AH.BH + AL.BH + AH.BL (per-acc product order fixed)
//   - update: 4 separately-rounded f32 ops (#pragma clang fp contract(off))
//   - wrap: branch-free, boundary-exact (|x| >= f32(pi) predicate)
//   - HW __sincosf only on paths attenuated by eff_dt*scale ~1e-3

#define B_TOTAL 65536
#define NOSC 60
#define STEPS 10

using short4v = __attribute__((ext_vector_type(4))) short;
using floatx4 = __attribute__((ext_vector_type(4))) float;

#if __has_builtin(__builtin_amdgcn_perm)
__device__ __forceinline__ unsigned int perm_b32(unsigned int s0, unsigned int s1, unsigned int sel) {
    return __builtin_amdgcn_perm(s0, s1, sel);
}
#else
__device__ __forceinline__ unsigned int perm_b32(unsigned int s0, unsigned int s1, unsigned int sel) {
    unsigned long long pool = ((unsigned long long)s0 << 32) | s1;
    unsigned int r = 0;
#pragma unroll
    for (int b = 0; b < 4; ++b) {
        unsigned int s = (sel >> (8 * b)) & 0xff;
        r |= ((unsigned int)((pool >> (8 * s)) & 0xff)) << (8 * b);
    }
    return r;
}
#endif

__device__ __forceinline__ unsigned int fbits(float x)        { return __builtin_bit_cast(unsigned int, x); }
__device__ __forceinline__ float        bitsf(unsigned int u) { return __builtin_bit_cast(float, u); }

// 16x16x16 bf16 MFMA (K=16). Guarded: builtin if present, else inline asm
// (v_mfma_f32_16x16x16_bf16 exists on gfx950 per ISA ref §10).
#if __has_builtin(__builtin_amdgcn_mfma_f32_16x16x16bf16_1k)
__device__ __forceinline__ floatx4 mfma16(short4v a, short4v b, floatx4 c) {
    return __builtin_amdgcn_mfma_f32_16x16x16bf16_1k(a, b, c, 0, 0, 0);
}
#else
__device__ __forceinline__ floatx4 mfma16(short4v a, short4v b, floatx4 c) {
    asm("v_mfma_f32_16x16x16_bf16 %0, %1, %2, %0" : "+v"(c) : "v"(a), "v"(b));
    return c;
}
#endif

// pack bf16-hi(a) into low half, bf16-hi(b) into high half of one b32
__device__ __forceinline__ unsigned int pack_hi_pair(float a, float b) {
    return perm_b32(fbits(b), fbits(a), 0x07060302u);
}

__global__ __launch_bounds__(256)
void kuramoto_kernel(const float* __restrict__ theta_in,
                     const float* __restrict__ Kmat,
                     const float* __restrict__ omega,
                     const float* __restrict__ p_kglobal,
                     const float* __restrict__ p_cmod,
                     const float* __restrict__ p_gate,
                     const float* __restrict__ p_slow,
                     const float* __restrict__ p_dsneg,
                     const float* __restrict__ p_relax,
                     float* __restrict__ theta_out,
                     float* __restrict__ coh_out)
{
    const int lane = threadIdx.x & 63;
    const int wid  = threadIdx.x >> 6;   // wave within block: 4 independent waves
    const int lidx = lane & 15;          // batch within tile
    const int quad = lane >> 4;          // 0..3

    const float kglobal = p_kglobal[0];
    const float cmod    = p_cmod[0];
    const float gate    = p_gate[0];
    const float slow    = p_slow[0];
    const float dsneg   = p_dsneg[0];
    const float relax   = p_relax[0];

    float eff_dt, scale;
    {
#pragma clang fp contract(off)
        const float a     = slow * relax;
        const float b     = 1.0f + a;
        const float crit  = 1.0f / b;
        eff_dt            = 0.1f * crit;
        const float boost = 1.0f + gate * dsneg;
        scale             = (kglobal * boost) / 60.0f;
    }

    const int batch0 = (blockIdx.x * 4 + wid) * 16;
    const int brow   = (batch0 + lidx) * NOSC;

    // ---- A operand (loop-invariant): Ke = K*cmod in MFMA-A layout, hi/lo split.
    // A[m=i][k=j]: lane holds row i = nt*16 + lidx, k = kt*16 + quad*4 + j.
    short4v AH[4][4], AL[4][4];
#pragma unroll
    for (int nt = 0; nt < 4; ++nt) {
        const int i = nt * 16 + lidx;
        const bool okn = (i < NOSC);          // zero A rows >= 60 -> acc rows 60..63 = 0
#pragma unroll
        for (int kt = 0; kt < 4; ++kt) {
            const int k0 = kt * 16 + quad * 4;
            float kv[4];
            if (okn && (k0 + 3) < NOSC) {
                const float4 a = *(const float4*)(Kmat + i * NOSC + k0);
                kv[0] = a.x; kv[1] = a.y; kv[2] = a.z; kv[3] = a.w;
            } else {
#pragma unroll
                for (int j = 0; j < 4; ++j)
                    kv[j] = (okn && (k0 + j) < NOSC) ? Kmat[i * NOSC + k0 + j] : 0.0f;
            }
            short4v h, l;
#pragma unroll
            for (int j = 0; j < 4; ++j) {
                const float v = kv[j] * cmod;
                const unsigned int hb = fbits(v) & 0xffff0000u;
                const float rlo = v - bitsf(hb);
                h[j] = (short)(hb >> 16);
                l[j] = (short)(fbits(rlo) >> 16);
            }
            AH[nt][kt] = h;
            AL[nt][kt] = l;
        }
    }

    // ---- state in C/D layout of the transposed GEMM:
    // element (osc o = nt*16 + quad*4 + r, batch = batch0 + lidx)
    float th[4][4], sn[4][4], cn[4][4], omg[4][4];
#pragma unroll
    for (int nt = 0; nt < 4; ++nt) {
        const int o0 = nt * 16 + quad * 4;    // o0 in {0,4,..,56} or 60 (pad)
        if (o0 + 3 < NOSC) {
            const float4 tv = *(const float4*)(theta_in + brow + o0);
            const float4 ov = *(const float4*)(omega + o0);
            th[nt][0] = tv.x; th[nt][1] = tv.y; th[nt][2] = tv.z; th[nt][3] = tv.w;
            omg[nt][0] = ov.x; omg[nt][1] = ov.y; omg[nt][2] = ov.z; omg[nt][3] = ov.w;
        } else {
#pragma unroll
            for (int r = 0; r < 4; ++r) { th[nt][r] = 0.0f; omg[nt][r] = 0.0f; }
        }
#pragma unroll
        for (int r = 0; r < 4; ++r)
            __sincosf(th[nt][r], &sn[nt][r], &cn[nt][r]);
    }

    // wrap constants (boundary-exact, see R3 notes)
    const float PI_F = 3.14159274101257324f;
    const float C_HI = 6.28318548202514648f;    // f32(2pi)
    const float C_LO = -1.7484556e-7f;          // 2pi - C_HI (f64-accurate)

    for (int t = 0; t < STEPS; ++t) {
        floatx4 accS[4], accC[4];
#pragma unroll
        for (int nt = 0; nt < 4; ++nt) { accS[nt] = (floatx4)0.0f; accC[nt] = (floatx4)0.0f; }

#pragma unroll
        for (int kt = 0; kt < 4; ++kt) {
            // B operand for k-tile kt: B[k = kt*16 + quad*4 + j][n = lidx]
            // == this thread's own state at (nt==kt, r==j). Zero data movement.
            union PU { unsigned int u[2]; short4v v; };
            PU bsh, bsl, bch, bcl;
            float slo[4], clo[4];
#pragma unroll
            for (int r = 0; r < 4; ++r) {
                const unsigned int us = fbits(sn[kt][r]);
                slo[r] = sn[kt][r] - bitsf(us & 0xffff0000u);
                const unsigned int uc = fbits(cn[kt][r]);
                clo[r] = cn[kt][r] - bitsf(uc & 0xffff0000u);
            }
            bsh.u[0] = pack_hi_pair(sn[kt][0], sn[kt][1]);
            bsh.u[1] = pack_hi_pair(sn[kt][2], sn[kt][3]);
            bsl.u[0] = pack_hi_pair(slo[0], slo[1]);
            bsl.u[1] = pack_hi_pair(slo[2], slo[3]);
            bch.u[0] = pack_hi_pair(cn[kt][0], cn[kt][1]);
            bch.u[1] = pack_hi_pair(cn[kt][2], cn[kt][3]);
            bcl.u[0] = pack_hi_pair(clo[0], clo[1]);
            bcl.u[1] = pack_hi_pair(clo[2], clo[3]);

            // product-major, S/C interleaved: same-acc reuse distance = 8 MFMAs.
            // Per-acc product order unchanged vs R4 (H.BH, L.BH, H.BL).
#pragma unroll
            for (int nt = 0; nt < 4; ++nt) accS[nt] = mfma16(AH[nt][kt], bsh.v, accS[nt]);
#pragma unroll
            for (int nt = 0; nt < 4; ++nt) accC[nt] = mfma16(AH[nt][kt], bch.v, accC[nt]);
#pragma unroll
            for (int nt = 0; nt < 4; ++nt) accS[nt] = mfma16(AL[nt][kt], bsh.v, accS[nt]);
#pragma unroll
            for (int nt = 0; nt < 4; ++nt) accC[nt] = mfma16(AL[nt][kt], bch.v, accC[nt]);
#pragma unroll
            for (int nt = 0; nt < 4; ++nt) accS[nt] = mfma16(AH[nt][kt], bsl.v, accS[nt]);
#pragma unroll
            for (int nt = 0; nt < 4; ++nt) accC[nt] = mfma16(AH[nt][kt], bcl.v, accC[nt]);
        }

        // ---- update: ref-exact association + boundary-exact wrap
#pragma unroll
        for (int nt = 0; nt < 4; ++nt) {
#pragma unroll
            for (int r = 0; r < 4; ++r) {
                const float S = accS[nt][r];
                const float C = accC[nt][r];
                const float coup = cn[nt][r] * S - sn[nt][r] * C;  // approx path: fma ok
                float nth;
                {
#pragma clang fp contract(off)
                    const float t1 = scale * coup;       // np: scale*coupling_sum
                    const float t2 = omg[nt][r] + t1;    // np: omega + ...
                    const float t3 = eff_dt * t2;        // np: eff_dt * (...)
                    nth = th[nt][r] + t3;                // np: th + ...
                }
                float n = 0.0f;
                n = (nth >=  PI_F) ?  1.0f : n;
                n = (nth <= -PI_F) ? -1.0f : n;
                float y = fmaf(n, -C_HI, nth);
                y = fmaf(n, -C_LO, y);
                th[nt][r] = y;
                __sincosf(y, &sn[nt][r], &cn[nt][r]);
            }
        }
    }

    // ---- epilogue: store wrapped theta (float4 per nt, pad tile skipped)
#pragma unroll
    for (int nt = 0; nt < 4; ++nt) {
        const int o0 = nt * 16 + quad * 4;
        if (o0 + 3 < NOSC) {
            float4 tv;
            tv.x = th[nt][0]; tv.y = th[nt][1]; tv.z = th[nt][2]; tv.w = th[nt][3];
            *(float4*)(theta_out + brow + o0) = tv;
        }
    }

    // ---- coherence: batch = lidx; thread holds 16 of its 60 osc, other 48
    // live in the 3 sibling quads -> 2 shfl_xor hops (16, 32) reduce.
    float pc = 0.0f, ps = 0.0f;
#pragma unroll
    for (int nt = 0; nt < 4; ++nt) {
        if (nt * 16 + quad * 4 < NOSC) {   // skip pad osc 60..63 (cos(0)=1!)
#pragma unroll
            for (int r = 0; r < 4; ++r) { pc += cn[nt][r]; ps += sn[nt][r]; }
        }
    }
    pc += __shfl_xor(pc, 16);
    ps += __shfl_xor(ps, 16);
    pc += __shfl_xor(pc, 32);
    ps += __shfl_xor(ps, 32);
    if (quad == 0) {
        const float cm = pc / 60.0f;
        const float sm = ps / 60.0f;
        coh_out[batch0 + lidx] = sqrtf(cm * cm + sm * sm);
    }
}

extern "C" void kernel_launch(void* const* d_in, const int* in_sizes, int n_in,
                              void* d_out, int out_size, void* d_ws, size_t ws_size,
                              hipStream_t stream) {
    const float* theta = (const float*)d_in[0];
    const float* Kmat  = (const float*)d_in[1];
    const float* omg   = (const float*)d_in[2];
    const float* kg    = (const float*)d_in[3];
    const float* cmod  = (const float*)d_in[4];
    const float* gate  = (const float*)d_in[5];
    const float* slow  = (const float*)d_in[6];
    const float* dsn   = (const float*)d_in[7];
    const float* relax = (const float*)d_in[8];
    float* out = (float*)d_out;

    kuramoto_kernel<<<dim3(B_TOTAL / 64), dim3(256), 0, stream>>>(
        theta, Kmat, omg, kg, cmod, gate, slow, dsn, relax,
        out, out + (size_t)B_TOTAL * NOSC);
}

// Round 4
// 126.063 us; speedup vs baseline: 1.4345x; 1.0151x over previous
//
#include <hip/hip_runtime.h>
#include <stdint.h>
#include <math.h>

// Kuramoto dynamics, B=65536 x N=60, 10 steps.
// R7: dual-tile in-wave software pipeline.
//   R6 post-mortem: counters show VALUBusy 49% + MfmaUtil 39% ~= 88% SUM --
//   the MFMA burst and the VALU burst (sincos/split/pack/update) ALTERNATE
//   instead of overlapping (few, phase-correlated waves/SIMD). Wall ~= VALU
//   time + MFMA time.
//   Fix: each wave owns TWO independent 16-batch tiles and pipelines them:
//     MFMA_A(0); for t: { MFMA_B(t); UPDATE_A(t); MFMA_A(t+1); UPDATE_B(t) }
//   Every MFMA burst sits next to an independent VALU update -> the two pipes
//   co-issue WITHIN one wave, independent of residency. Wave count halves.
//   No launch-bounds min clause: allocator free up to 512 VGPR -> worst case
//   1 wave/SIMD, never scratch-spills (R5's failure mode excluded).
//   t-loop kept rolled (#pragma unroll 1) so ~6KB body fits I$.
// Numerics bitwise-identical per batch to R6/R4/R3:
//   - 3-pass split MFMA: AH.BH + AL.BH + AH.BL, kt order 0..3, product-major
//     S/C-interleaved groups (same-acc reuse distance 8)
//   - update: 4 separately-rounded f32 ops (#pragma clang fp contract(off))
//   - wrap: branch-free, boundary-exact (|x| >= f32(pi) predicate)
//   - HW __sincosf only on paths attenuated by eff_dt*scale ~1e-3

#define B_TOTAL 65536
#define NOSC 60
#define STEPS 10

using short4v = __attribute__((ext_vector_type(4))) short;
using floatx4 = __attribute__((ext_vector_type(4))) float;

#if __has_builtin(__builtin_amdgcn_perm)
__device__ __forceinline__ unsigned int perm_b32(unsigned int s0, unsigned int s1, unsigned int sel) {
    return __builtin_amdgcn_perm(s0, s1, sel);
}
#else
__device__ __forceinline__ unsigned int perm_b32(unsigned int s0, unsigned int s1, unsigned int sel) {
    unsigned long long pool = ((unsigned long long)s0 << 32) | s1;
    unsigned int r = 0;
#pragma unroll
    for (int b = 0; b < 4; ++b) {
        unsigned int s = (sel >> (8 * b)) & 0xff;
        r |= ((unsigned int)((pool >> (8 * s)) & 0xff)) << (8 * b);
    }
    return r;
}
#endif

__device__ __forceinline__ unsigned int fbits(float x)        { return __builtin_bit_cast(unsigned int, x); }
__device__ __forceinline__ float        bitsf(unsigned int u) { return __builtin_bit_cast(float, u); }

#if __has_builtin(__builtin_amdgcn_mfma_f32_16x16x16bf16_1k)
__device__ __forceinline__ floatx4 mfma16(short4v a, short4v b, floatx4 c) {
    return __builtin_amdgcn_mfma_f32_16x16x16bf16_1k(a, b, c, 0, 0, 0);
}
#else
__device__ __forceinline__ floatx4 mfma16(short4v a, short4v b, floatx4 c) {
    asm("v_mfma_f32_16x16x16_bf16 %0, %1, %2, %0" : "+v"(c) : "v"(a), "v"(b));
    return c;
}
#endif

// pack bf16-hi(a) into low half, bf16-hi(b) into high half of one b32
__device__ __forceinline__ unsigned int pack_hi_pair(float a, float b) {
    return perm_b32(fbits(b), fbits(a), 0x07060302u);
}

// ---- one tile's coupling GEMM: accS/accC = Ke . {sin,cos}^T (3-product split).
// First products take Z (fresh acc) -- no per-step acc zero-init movs.
__device__ __forceinline__ void mfma_tile(const short4v (&AH)[4][4], const short4v (&AL)[4][4],
                                          const float (&sn)[4][4], const float (&cn)[4][4],
                                          floatx4 (&accS)[4], floatx4 (&accC)[4])
{
    const floatx4 Z = (floatx4)0.0f;
#pragma unroll
    for (int kt = 0; kt < 4; ++kt) {
        union PU { unsigned int u[2]; short4v v; };
        PU bsh, bsl, bch, bcl;
        float slo[4], clo[4];
#pragma unroll
        for (int r = 0; r < 4; ++r) {
            const unsigned int us = fbits(sn[kt][r]);
            slo[r] = sn[kt][r] - bitsf(us & 0xffff0000u);
            const unsigned int uc = fbits(cn[kt][r]);
            clo[r] = cn[kt][r] - bitsf(uc & 0xffff0000u);
        }
        bsh.u[0] = pack_hi_pair(sn[kt][0], sn[kt][1]);
        bsh.u[1] = pack_hi_pair(sn[kt][2], sn[kt][3]);
        bsl.u[0] = pack_hi_pair(slo[0], slo[1]);
        bsl.u[1] = pack_hi_pair(slo[2], slo[3]);
        bch.u[0] = pack_hi_pair(cn[kt][0], cn[kt][1]);
        bch.u[1] = pack_hi_pair(cn[kt][2], cn[kt][3]);
        bcl.u[0] = pack_hi_pair(clo[0], clo[1]);
        bcl.u[1] = pack_hi_pair(clo[2], clo[3]);

        // product-major, S/C interleaved: same-acc reuse distance = 8 MFMAs.
        // Per-acc product order: (per kt) H.BH, L.BH, H.BL -- same as R4/R6.
#pragma unroll
        for (int nt = 0; nt < 4; ++nt) accS[nt] = mfma16(AH[nt][kt], bsh.v, (kt == 0) ? Z : accS[nt]);
#pragma unroll
        for (int nt = 0; nt < 4; ++nt) accC[nt] = mfma16(AH[nt][kt], bch.v, (kt == 0) ? Z : accC[nt]);
#pragma unroll
        for (int nt = 0; nt < 4; ++nt) accS[nt] = mfma16(AL[nt][kt], bsh.v, accS[nt]);
#pragma unroll
        for (int nt = 0; nt < 4; ++nt) accC[nt] = mfma16(AL[nt][kt], bch.v, accC[nt]);
#pragma unroll
        for (int nt = 0; nt < 4; ++nt) accS[nt] = mfma16(AH[nt][kt], bsl.v, accS[nt]);
#pragma unroll
        for (int nt = 0; nt < 4; ++nt) accC[nt] = mfma16(AH[nt][kt], bcl.v, accC[nt]);
    }
}

// ---- one tile's pointwise update: ref-exact association + boundary-exact wrap
__device__ __forceinline__ void update_tile(float (&th)[4][4], float (&sn)[4][4], float (&cn)[4][4],
                                            const float (&omg)[4][4],
                                            const floatx4 (&accS)[4], const floatx4 (&accC)[4],
                                            float scale, float eff_dt)
{
    const float PI_F = 3.14159274101257324f;
    const float C_HI = 6.28318548202514648f;    // f32(2pi)
    const float C_LO = -1.7484556e-7f;          // 2pi - C_HI (f64-accurate)
#pragma unroll
    for (int nt = 0; nt < 4; ++nt) {
#pragma unroll
        for (int r = 0; r < 4; ++r) {
            const float S = accS[nt][r];
            const float C = accC[nt][r];
            const float coup = cn[nt][r] * S - sn[nt][r] * C;  // approx path: fma ok
            float nth;
            {
#pragma clang fp contract(off)
                const float t1 = scale * coup;       // np: scale*coupling_sum
                const float t2 = omg[nt][r] + t1;    // np: omega + ...
                const float t3 = eff_dt * t2;        // np: eff_dt * (...)
                nth = th[nt][r] + t3;                // np: th + ...
            }
            float n = 0.0f;
            n = (nth >=  PI_F) ?  1.0f : n;
            n = (nth <= -PI_F) ? -1.0f : n;
            float y = fmaf(n, -C_HI, nth);
            y = fmaf(n, -C_LO, y);
            th[nt][r] = y;
            __sincosf(y, &sn[nt][r], &cn[nt][r]);
        }
    }
}

__global__ __launch_bounds__(64)
void kuramoto_kernel(const float* __restrict__ theta_in,
                     const float* __restrict__ Kmat,
                     const float* __restrict__ omega,
                     const float* __restrict__ p_kglobal,
                     const float* __restrict__ p_cmod,
                     const float* __restrict__ p_gate,
                     const float* __restrict__ p_slow,
                     const float* __restrict__ p_dsneg,
                     const float* __restrict__ p_relax,
                     float* __restrict__ theta_out,
                     float* __restrict__ coh_out)
{
    const int lane = threadIdx.x & 63;
    const int lidx = lane & 15;          // batch within tile
    const int quad = lane >> 4;          // 0..3

    const float kglobal = p_kglobal[0];
    const float cmod    = p_cmod[0];
    const float gate    = p_gate[0];
    const float slow    = p_slow[0];
    const float dsneg   = p_dsneg[0];
    const float relax   = p_relax[0];

    float eff_dt, scale;
    {
#pragma clang fp contract(off)
        const float a     = slow * relax;
        const float b     = 1.0f + a;
        const float crit  = 1.0f / b;
        eff_dt            = 0.1f * crit;
        const float boost = 1.0f + gate * dsneg;
        scale             = (kglobal * boost) / 60.0f;
    }

    const int batch0A = blockIdx.x * 32;
    const int batch0B = batch0A + 16;
    const int browA   = (batch0A + lidx) * NOSC;
    const int browB   = (batch0B + lidx) * NOSC;

    // ---- A operand (loop-invariant, shared by both tiles): Ke = K*cmod,
    // MFMA-A layout, hi/lo split. lane row i = nt*16+lidx, k = kt*16+quad*4+j.
    short4v AH[4][4], AL[4][4];
#pragma unroll
    for (int nt = 0; nt < 4; ++nt) {
        const int i = nt * 16 + lidx;
        const bool okn = (i < NOSC);          // zero A rows >= 60 -> acc rows 60..63 = 0
#pragma unroll
        for (int kt = 0; kt < 4; ++kt) {
            const int k0 = kt * 16 + quad * 4;
            float kv[4];
            if (okn && (k0 + 3) < NOSC) {
                const float4 a = *(const float4*)(Kmat + i * NOSC + k0);
                kv[0] = a.x; kv[1] = a.y; kv[2] = a.z; kv[3] = a.w;
            } else {
#pragma unroll
                for (int j = 0; j < 4; ++j)
                    kv[j] = (okn && (k0 + j) < NOSC) ? Kmat[i * NOSC + k0 + j] : 0.0f;
            }
            short4v h, l;
#pragma unroll
            for (int j = 0; j < 4; ++j) {
                const float v = kv[j] * cmod;
                const unsigned int hb = fbits(v) & 0xffff0000u;
                const float rlo = v - bitsf(hb);
                h[j] = (short)(hb >> 16);
                l[j] = (short)(fbits(rlo) >> 16);
            }
            AH[nt][kt] = h;
            AL[nt][kt] = l;
        }
    }

    // ---- state, C/D layout: element (osc o = nt*16 + quad*4 + r, batch lidx)
    float thA[4][4], snA[4][4], cnA[4][4];
    float thB[4][4], snB[4][4], cnB[4][4];
    float omg[4][4];                       // osc-indexed: shared by both tiles
#pragma unroll
    for (int nt = 0; nt < 4; ++nt) {
        const int o0 = nt * 16 + quad * 4;    // {0,4,..,56} or 60 (pad)
        if (o0 + 3 < NOSC) {
            const float4 ov = *(const float4*)(omega + o0);
            omg[nt][0] = ov.x; omg[nt][1] = ov.y; omg[nt][2] = ov.z; omg[nt][3] = ov.w;
            const float4 ta = *(const float4*)(theta_in + browA + o0);
            thA[nt][0] = ta.x; thA[nt][1] = ta.y; thA[nt][2] = ta.z; thA[nt][3] = ta.w;
            const float4 tb = *(const float4*)(theta_in + browB + o0);
            thB[nt][0] = tb.x; thB[nt][1] = tb.y; thB[nt][2] = tb.z; thB[nt][3] = tb.w;
        } else {
#pragma unroll
            for (int r = 0; r < 4; ++r) {
                omg[nt][r] = 0.0f; thA[nt][r] = 0.0f; thB[nt][r] = 0.0f;
            }
        }
#pragma unroll
        for (int r = 0; r < 4; ++r) {
            __sincosf(thA[nt][r], &snA[nt][r], &cnA[nt][r]);
            __sincosf(thB[nt][r], &snB[nt][r], &cnB[nt][r]);
        }
    }

    floatx4 accSA[4], accCA[4], accSB[4], accCB[4];

    // ---- software pipeline: MFMA of one tile overlaps UPDATE of the other.
    mfma_tile(AH, AL, snA, cnA, accSA, accCA);            // A step 0
#pragma unroll 1
    for (int t = 0; t < STEPS - 1; ++t) {
        mfma_tile(AH, AL, snB, cnB, accSB, accCB);        // B step t
        update_tile(thA, snA, cnA, omg, accSA, accCA, scale, eff_dt);  // A -> t+1
        mfma_tile(AH, AL, snA, cnA, accSA, accCA);        // A step t+1
        update_tile(thB, snB, cnB, omg, accSB, accCB, scale, eff_dt);  // B -> t+1
    }
    mfma_tile(AH, AL, snB, cnB, accSB, accCB);            // B step 9
    update_tile(thA, snA, cnA, omg, accSA, accCA, scale, eff_dt);      // A -> 10
    update_tile(thB, snB, cnB, omg, accSB, accCB, scale, eff_dt);      // B -> 10

    // ---- epilogue: store wrapped theta (float4 per nt, pad tile skipped)
#pragma unroll
    for (int nt = 0; nt < 4; ++nt) {
        const int o0 = nt * 16 + quad * 4;
        if (o0 + 3 < NOSC) {
            float4 ta, tb;
            ta.x = thA[nt][0]; ta.y = thA[nt][1]; ta.z = thA[nt][2]; ta.w = thA[nt][3];
            *(float4*)(theta_out + browA + o0) = ta;
            tb.x = thB[nt][0]; tb.y = thB[nt][1]; tb.z = thB[nt][2]; tb.w = thB[nt][3];
            *(float4*)(theta_out + browB + o0) = tb;
        }
    }

    // ---- coherence per tile: batch = lidx; 16 osc local, 48 in sibling quads.
    float pcA = 0.0f, psA = 0.0f, pcB = 0.0f, psB = 0.0f;
#pragma unroll
    for (int nt = 0; nt < 4; ++nt) {
        if (nt * 16 + quad * 4 < NOSC) {   // skip pad osc 60..63 (cos(0)=1!)
#pragma unroll
            for (int r = 0; r < 4; ++r) {
                pcA += cnA[nt][r]; psA += snA[nt][r];
                pcB += cnB[nt][r]; psB += snB[nt][r];
            }
        }
    }
    pcA += __shfl_xor(pcA, 16); psA += __shfl_xor(psA, 16);
    pcA += __shfl_xor(pcA, 32); psA += __shfl_xor(psA, 32);
    pcB += __shfl_xor(pcB, 16); psB += __shfl_xor(psB, 16);
    pcB += __shfl_xor(pcB, 32); psB += __shfl_xor(psB, 32);
    if (quad == 0) {
        const float cmA = pcA / 60.0f, smA = psA / 60.0f;
        coh_out[batch0A + lidx] = sqrtf(cmA * cmA + smA * smA);
        const float cmB = pcB / 60.0f, smB = psB / 60.0f;
        coh_out[batch0B + lidx] = sqrtf(cmB * cmB + smB * smB);
    }
}

extern "C" void kernel_launch(void* const* d_in, const int* in_sizes, int n_in,
                              void* d_out, int out_size, void* d_ws, size_t ws_size,
                              hipStream_t stream) {
    const float* theta = (const float*)d_in[0];
    const float* Kmat  = (const float*)d_in[1];
    const float* omg   = (const float*)d_in[2];
    const float* kg    = (const float*)d_in[3];
    const float* cmod  = (const float*)d_in[4];
    const float* gate  = (const float*)d_in[5];
    const float* slow  = (const float*)d_in[6];
    const float* dsn   = (const float*)d_in[7];
    const float* relax = (const float*)d_in[8];
    float* out = (float*)d_out;

    kuramoto_kernel<<<dim3(B_TOTAL / 32), dim3(64), 0, stream>>>(
        theta, Kmat, omg, kg, cmod, gate, slow, dsn, relax,
        out, out + (size_t)B_TOTAL * NOSC);
}